// Round 9
// baseline (321.095 us; speedup 1.0000x reference)
//
#include <hip/hip_runtime.h>
#include <stdint.h>

typedef __attribute__((ext_vector_type(4))) float floatx4;
typedef __attribute__((ext_vector_type(8))) __bf16 bf16x8;
typedef __attribute__((ext_vector_type(4))) short short4v;

#define DEV __device__ __forceinline__

constexpr int HB = 12;        // heads
constexpr int LSEQ = 2048;    // LQ == LK
constexpr int DMODEL = 768;
constexpr int MROWS = 8192;   // B * LQ
constexpr float QSCALE = 0.125f * 1.44269504088896f;  // 1/sqrt(64) * log2(e)

DEV short f2bf(float f) {
  union { float f; uint32_t u; } x; x.f = f;
  uint32_t r = x.u + 0x7FFFu + ((x.u >> 16) & 1u);
  return (short)(r >> 16);
}

DEV float bf2f(short s) {
  union { uint32_t u; float f; } x; x.u = ((uint32_t)(uint16_t)s) << 16;
  return x.f;
}

typedef __attribute__((address_space(1))) void as1_void;
typedef __attribute__((address_space(3))) void as3_void;

DEV void gload_lds16(const void* g, void* l) {
  __builtin_amdgcn_global_load_lds((as1_void*)(uintptr_t)g, (as3_void*)l, 16, 0, 0);
}

// ---------------------------------------------------------------- prep (weight T + vlens + activation cvt)
// flat grid: [0,3456) weight transposes, [3456,3460) vlens, [3460,21892) f32->bf16 cvt
__global__ __launch_bounds__(256)
void prep_k(const float* w0, const float* w1, const float* w2,
            const float* w3, const float* w4, const float* w5,
            short* o0, short* o1, short* o2, short* o3, short* o4, short* o5,
            const int* __restrict__ mask, int* __restrict__ vl,
            const float* __restrict__ aq, const float* __restrict__ ak, const float* __restrict__ av,
            short* __restrict__ dq, short* __restrict__ dk, short* __restrict__ dv)
{
  const int id = blockIdx.x;
  if (id >= 3460) {                       // activation cast
    const int cid = id - 3460;
    const int t = cid / 6144, inner = cid % 6144;
    const float* s = (t == 0) ? aq : (t == 1) ? ak : av;
    short* d = (t == 0) ? dq : (t == 1) ? dk : dv;
    const size_t i = ((size_t)inner * 256 + threadIdx.x) * 4;
    const float4 v = *(const float4*)(s + i);
    short4 r; r.x = f2bf(v.x); r.y = f2bf(v.y); r.z = f2bf(v.z); r.w = f2bf(v.w);
    *(short4*)(d + i) = r;
    return;
  }
  if (id >= 3456) {                       // valid lengths
    const int b = id - 3456;
    int s = 0;
    for (int i = threadIdx.x; i < LSEQ; i += 256) s += (mask[b * LSEQ + i] != 0) ? 1 : 0;
#pragma unroll
    for (int o = 32; o >= 1; o >>= 1) s += __shfl_xor(s, o);
    __shared__ int red[4];
    const int lane = threadIdx.x & 63, wave = threadIdx.x >> 6;
    if (lane == 0) red[wave] = s;
    __syncthreads();
    if (threadIdx.x == 0) vl[b] = red[0] + red[1] + red[2] + red[3];
    return;
  }
  const int slice = id / 576, rem = id % 576;   // weight transpose+cast
  const float* W; short* O;
  switch (slice) {
    case 0: W = w0; O = o0; break;
    case 1: W = w1; O = o1; break;
    case 2: W = w2; O = o2; break;
    case 3: W = w3; O = o3; break;
    case 4: W = w4; O = o4; break;
    default: W = w5; O = o5; break;
  }
  __shared__ float t[32][33];
  const int tx = threadIdx.x & 31, ty = threadIdx.x >> 5; // 32 x 8
  const int n0 = (rem % 24) * 32, k0 = (rem / 24) * 32;
#pragma unroll
  for (int i = 0; i < 4; ++i)
    t[ty + i * 8][tx] = W[(size_t)(k0 + ty + i * 8) * DMODEL + n0 + tx];
  __syncthreads();
#pragma unroll
  for (int i = 0; i < 4; ++i)
    O[(size_t)(n0 + ty + i * 8) * DMODEL + k0 + tx] = f2bf(t[tx][ty + i * 8]);
}

// ---------------------------------------------------------------- GEMM
// r6 proven core (64x128 tile, BK=64 as 2x32 halves, 16 MFMA per barrier-pair)
// + PREFETCH DISTANCE 2 via tri-buffer: at iter kt stage tile kt+2, wait
// vmcnt(12) so tiles kt+1,kt+2 (12 loads) stay in flight across barriers.
// LDS 72 KB -> 2 blocks/CU (measured effective occupancy was ~2 anyway);
// per-wave latency tolerance doubles: stall = max(0, L - 2*D_iter).
enum { EPI_QKV = 0, EPI_PLAIN = 2, EPI_BIAS_RELU = 3, EPI_Y = 4 };

template <int EPI>
__global__ __launch_bounds__(256)
void gemm_k(const short* __restrict__ A0, const short* __restrict__ A1, const short* __restrict__ A2,
            const short* __restrict__ B0, const short* __restrict__ B1, const short* __restrict__ B2,
            const float* __restrict__ bias, const short* __restrict__ resid,
            void* __restrict__ o0, void* __restrict__ o1, void* __restrict__ o2)
{
  __shared__ __align__(16) short As[3][2][64 * 32];    // [buf][half] 24 KB
  __shared__ __align__(16) short Bs[3][2][128 * 32];   // [buf][half] 48 KB
  const short* A = A0;
  const short* Bt = B0;
  if constexpr (EPI == EPI_QKV) {
    if (blockIdx.z == 1) { A = A1; Bt = B1; }
    else if (blockIdx.z == 2) { A = A2; Bt = B2; }
  }
  const int tid = threadIdx.x;
  const int lane = tid & 63, wave = tid >> 6;
  const int wm = wave >> 1, wn = wave & 1;
  const int m0 = blockIdx.x * 64, n0 = blockIdx.y * 128;   // x = m-panel (XCD affinity)
  const int col = lane & 15, quad = lane >> 4;
  const int sr = lane >> 2;            // staging row within 16-row chunk
  const int sk = (lane & 3) * 8;       // staging k offset (8 bf16 = 16B)

  const short* Arow = A + (size_t)(m0 + wave * 16 + sr) * DMODEL + sk;
  const short* Brow0 = Bt + (size_t)(n0 + (wave * 2 + 0) * 16 + sr) * DMODEL + sk;
  const short* Brow1 = Bt + (size_t)(n0 + (wave * 2 + 1) * 16 + sr) * DMODEL + sk;

  auto stage = [&](int kt, int buf) {
    const int k0 = kt * 64;
#pragma unroll
    for (int h = 0; h < 2; ++h) {
      gload_lds16(Arow + k0 + h * 32, &As[buf][h][wave * 512]);
      gload_lds16(Brow0 + k0 + h * 32, &Bs[buf][h][(wave * 2 + 0) * 512]);
      gload_lds16(Brow1 + k0 + h * 32, &Bs[buf][h][(wave * 2 + 1) * 512]);
    }
  };

  floatx4 acc[2][4] = {};

  stage(0, 0);
  stage(1, 1);
  int cur = 0, sb = 2;   // sb = buffer for next staged tile
  for (int kt = 0; kt < 12; ++kt) {
    // barrier A: all waves finished reading buf sb (last read in iter kt-1)
    asm volatile("s_barrier" ::: "memory");
    if (kt < 10) {
      stage(kt + 2, sb);
      asm volatile("s_waitcnt vmcnt(12)" ::: "memory");  // tile-kt landed; kt+1,kt+2 in flight
    } else if (kt == 10) {
      asm volatile("s_waitcnt vmcnt(6)" ::: "memory");
    } else {
      asm volatile("s_waitcnt vmcnt(0)" ::: "memory");
    }
    // barrier B: ALL waves' tile-kt loads have landed in LDS
    asm volatile("s_barrier" ::: "memory");
#pragma unroll
    for (int h = 0; h < 2; ++h) {
      bf16x8 af[2], bfr[4];
#pragma unroll
      for (int t = 0; t < 2; ++t)
        af[t] = *(const bf16x8*)&As[cur][h][(wm * 32 + t * 16 + col) * 32 + quad * 8];
#pragma unroll
      for (int t = 0; t < 4; ++t)
        bfr[t] = *(const bf16x8*)&Bs[cur][h][(wn * 64 + t * 16 + col) * 32 + quad * 8];
#pragma unroll
      for (int mt = 0; mt < 2; ++mt)
#pragma unroll
        for (int nt = 0; nt < 4; ++nt)
          acc[mt][nt] = __builtin_amdgcn_mfma_f32_16x16x32_bf16(af[mt], bfr[nt], acc[mt][nt], 0, 0, 0);
    }
    cur = (cur == 2) ? 0 : cur + 1;
    sb  = (sb == 2) ? 0 : sb + 1;
  }

#pragma unroll
  for (int mt = 0; mt < 2; ++mt) {
#pragma unroll
    for (int nt = 0; nt < 4; ++nt) {
#pragma unroll
      for (int r = 0; r < 4; ++r) {
        const int m = m0 + wm * 32 + mt * 16 + quad * 4 + r;
        const int n = n0 + wn * 64 + nt * 16 + col;
        float v = acc[mt][nt][r];
        if constexpr (EPI == EPI_QKV) {
          const int b = m >> 11, l = m & 2047, h = n >> 6, dh = n & 63;
          const int z = blockIdx.z;
          if (z == 0) {
            ((short*)o0)[((size_t)(b * HB + h) * LSEQ + l) * 64 + dh] = f2bf(v * QSCALE);
          } else if (z == 1) {
            ((short*)o1)[((size_t)(b * HB + h) * LSEQ + l) * 64 + dh] = f2bf(v);
          } else {
            ((short*)o2)[((size_t)(b * HB + h) * 64 + dh) * LSEQ + l] = f2bf(v);
          }
        } else if constexpr (EPI == EPI_PLAIN) {
          ((short*)o0)[(size_t)m * DMODEL + n] = f2bf(v);
        } else if constexpr (EPI == EPI_BIAS_RELU) {
          v += bias[n]; v = v > 0.f ? v : 0.f;
          ((short*)o0)[(size_t)m * DMODEL + n] = f2bf(v);
        } else { // EPI_Y: + bias + bf16 residual -> f32
          v += bias[n] + bf2f(resid[(size_t)m * DMODEL + n]);
          ((float*)o0)[(size_t)m * DMODEL + n] = v;
        }
      }
    }
  }
}

// ---------------------------------------------------------------- flash attention (S^T form)
// 64-row Q tile, grid 48x32 = 1536 blocks. S^T = K Q^T; P^T feeds 16x16x16 PV
// from registers; Q in registers; Vts XOR-swizzled; dbuf K/V ping-pong vmcnt(4).
__global__ __launch_bounds__(256)
void attn_k(const short* __restrict__ qw, const short* __restrict__ kw, const short* __restrict__ vtw,
            const int* __restrict__ vlens, short* __restrict__ outp)
{
  __shared__ __align__(16) short Ks[2][2][64][32];      // [buf][dh-half][kpos]  16 KB
  __shared__ __align__(16) short Vts[2][2][64][32];     // [buf][kp-half][dh]    16 KB (swizzled)

  const int tid = threadIdx.x;
  const int lane = tid & 63, wave = tid >> 6;
  const int col = lane & 15, quad = lane >> 4;
  const int bh = blockIdx.x, b = bh / HB, h = bh % HB;
  const int q0 = blockIdx.y * 64;
  const int vl = vlens[b];
  const int sr = lane >> 2, sk = (lane & 3) * 8;
  const int skv = ((lane & 3) ^ ((lane >> 3) & 3)) * 8;   // V staging swizzle (lane-const)
  const int swz = (col >> 1) & 3;                          // V read swizzle

  const short* qbase = qw  + (size_t)bh * LSEQ * 64;
  const short* kbase = kw  + (size_t)bh * LSEQ * 64;
  const short* vbase = vtw + (size_t)bh * 64 * LSEQ;

  // Q fragments direct to registers (per-wave rows q0 + wave*16 .. +15)
  bf16x8 qf[2];
#pragma unroll
  for (int ks = 0; ks < 2; ++ks)
    qf[ks] = *(const bf16x8*)(qbase + (size_t)(q0 + wave * 16 + col) * 64 + ks * 32 + quad * 8);

  auto stage = [&](int kt, int buf) {
#pragma unroll
    for (int i = 0; i < 2; ++i) {
      const int c = wave * 2 + i;        // 0..7
      const int hs = c >> 2, r0 = (c & 3) * 16;
      gload_lds16(kbase + (size_t)(kt * 64 + r0 + sr) * 64 + hs * 32 + sk, &Ks[buf][hs][r0][0]);
      gload_lds16(vbase + (size_t)(r0 + sr) * LSEQ + kt * 64 + hs * 32 + skv, &Vts[buf][hs][r0][0]);
    }
  };

  floatx4 oacc[4] = {};   // [d-chunk nt], O^T C-layout
  float li = 0.f;         // per-lane partial denominator (q = col)

  const int ktend = (vl > 0) ? ((vl + 63) >> 6) : (LSEQ / 64);

  stage(0, 0);
  for (int kt = 0; kt < ktend; ++kt) {
    const int cur = kt & 1;
    asm volatile("s_barrier" ::: "memory");
    if (kt + 1 < ktend) {
      stage(kt + 1, cur ^ 1);
      asm volatile("s_waitcnt vmcnt(4)" ::: "memory");   // tile-kt's 4 loads landed
    } else {
      asm volatile("s_waitcnt vmcnt(0)" ::: "memory");
    }
    asm volatile("s_barrier" ::: "memory");

    // S^T = K Q^T : sacc[kc], rows = kpos, cols = q
    floatx4 sacc[4] = {};
#pragma unroll
    for (int ks = 0; ks < 2; ++ks) {
      bf16x8 kf[4];
#pragma unroll
      for (int kc = 0; kc < 4; ++kc)
        kf[kc] = *(const bf16x8*)&Ks[cur][ks][kc * 16 + col][quad * 8];
#pragma unroll
      for (int kc = 0; kc < 4; ++kc)
        sacc[kc] = __builtin_amdgcn_mfma_f32_16x16x32_bf16(kf[kc], qf[ks], sacc[kc], 0, 0, 0);
    }

    // boundary tile: masked kpos rows -> -1e6 (exp2 -> exactly 0, = ref)
    if (kt * 64 + 64 > vl) {
#pragma unroll
      for (int kc = 0; kc < 4; ++kc) {
        const int pbase = kt * 64 + kc * 16 + quad * 4;
#pragma unroll
        for (int r = 0; r < 4; ++r) {
          const bool ok = (pbase + r) < vl;
          sacc[kc][r] = ok ? sacc[kc][r] : -1.0e6f;
        }
      }
    }

    // p = exp2(s); accumulate per-lane denominator; pack to bf16 B-frags
    short4v pf[4];
#pragma unroll
    for (int kc = 0; kc < 4; ++kc) {
      union { float f; uint32_t u; } p0, p1, p2, p3;
      p0.f = __builtin_amdgcn_exp2f(sacc[kc][0]);
      p1.f = __builtin_amdgcn_exp2f(sacc[kc][1]);
      p2.f = __builtin_amdgcn_exp2f(sacc[kc][2]);
      p3.f = __builtin_amdgcn_exp2f(sacc[kc][3]);
      li += (p0.f + p1.f) + (p2.f + p3.f);
      union { int2 i2; short4v s4; } pk;
      pk.i2.x = (int)__builtin_amdgcn_perm(p1.u, p0.u, 0x07060302u);  // {hi16(p1),hi16(p0)}
      pk.i2.y = (int)__builtin_amdgcn_perm(p3.u, p2.u, 0x07060302u);
      pf[kc] = pk.s4;
    }

    // O^T += V^T P^T via K=16 MFMA (P^T chunks are already B-operand layout)
#pragma unroll
    for (int nt = 0; nt < 4; ++nt) {
      short4v vf[4];
#pragma unroll
      for (int kc = 0; kc < 4; ++kc) {
        const int jb = (((kc & 1) * 2 + (quad >> 1)) ^ swz);
        vf[kc] = *(const short4v*)&Vts[cur][kc >> 1][nt * 16 + col][jb * 8 + (quad & 1) * 4];
      }
#pragma unroll
      for (int kc = 0; kc < 4; ++kc)
        oacc[nt] = __builtin_amdgcn_mfma_f32_16x16x16bf16_1k(vf[kc], pf[kc], oacc[nt], 0, 0, 0);
    }
  }

  // reduce denominator across quads (q = col is lane-resident)
  float t = li;
  t += __shfl_xor(t, 16);
  t += __shfl_xor(t, 32);
  const float rli = 1.0f / fmaxf(t, 1e-30f);

  // epilogue: O[q][d] from O^T C-layout; d contiguous -> b64 stores
  const int q = q0 + wave * 16 + col;
  short* orow = outp + ((size_t)b * LSEQ + q) * DMODEL + h * 64 + quad * 4;
#pragma unroll
  for (int nt = 0; nt < 4; ++nt) {
    short4 s;
    s.x = f2bf(oacc[nt][0] * rli);
    s.y = f2bf(oacc[nt][1] * rli);
    s.z = f2bf(oacc[nt][2] * rli);
    s.w = f2bf(oacc[nt][3] * rli);
    *(short4*)(orow + nt * 16) = s;
  }
}

// ---------------------------------------------------------------- layernorm
__global__ __launch_bounds__(256)
void ln_k(const float* __restrict__ y, const float* __restrict__ g, const float* __restrict__ be,
          float* __restrict__ o)
{
  const int row = blockIdx.x;
  const int tid = threadIdx.x;
  const float* yr = y + (size_t)row * DMODEL;
  float v[3];
  float s = 0.f, sq = 0.f;
#pragma unroll
  for (int i = 0; i < 3; ++i) { v[i] = yr[tid + i * 256]; s += v[i]; sq += v[i] * v[i]; }
#pragma unroll
  for (int off = 32; off >= 1; off >>= 1) { s += __shfl_xor(s, off); sq += __shfl_xor(sq, off); }
  __shared__ float red[8];
  const int lane = tid & 63, wave = tid >> 6;
  if (lane == 0) { red[wave] = s; red[4 + wave] = sq; }
  __syncthreads();
  s = red[0] + red[1] + red[2] + red[3];
  sq = red[4] + red[5] + red[6] + red[7];
  const float mu = s * (1.f / 768.f);
  const float var = sq * (1.f / 768.f) - mu * mu;
  const float rstd = rsqrtf(var + 1e-5f);
  float* orow = o + (size_t)row * DMODEL;
#pragma unroll
  for (int i = 0; i < 3; ++i) {
    const int c = tid + i * 256;
    orow[c] = (v[i] - mu) * rstd * g[c] + be[c];
  }
}

// ---------------------------------------------------------------- launch
extern "C" void kernel_launch(void* const* d_in, const int* in_sizes, int n_in,
                              void* d_out, int out_size, void* d_ws, size_t ws_size,
                              hipStream_t stream)
{
  const float* queries = (const float*)d_in[0];
  const float* keys    = (const float*)d_in[1];
  const float* values  = (const float*)d_in[2];
  const int*   mask    = (const int*)d_in[3];
  const float* Wq = (const float*)d_in[4];
  const float* Wk = (const float*)d_in[5];
  const float* Wv = (const float*)d_in[6];
  const float* Wo = (const float*)d_in[7];
  const float* W1 = (const float*)d_in[8];
  const float* b1 = (const float*)d_in[9];
  const float* W2 = (const float*)d_in[10];
  const float* b2 = (const float*)d_in[11];
  const float* ln_g = (const float*)d_in[12];
  const float* ln_b = (const float*)d_in[13];

  char* ws = (char*)d_ws;
  size_t off = 0;
  auto alloc = [&](size_t bytes) -> void* {
    void* p = ws + off;
    off = (off + bytes + 255) & ~(size_t)255;
    return p;
  };
  int* vlens = (int*)alloc(256);
  short* wt[6];
  for (int i = 0; i < 6; ++i) wt[i] = (short*)alloc((size_t)DMODEL * DMODEL * 2);
  constexpr size_t SB = (size_t)MROWS * DMODEL * 2;  // 12,582,912 (multiple of 256)
  short* xq  = (short*)alloc(SB);
  short* xk  = (short*)alloc(SB);
  short* xv  = (short*)alloc(SB);
  short* qw  = (short*)alloc(SB);
  short* kw  = (short*)alloc(SB);
  short* vtw = (short*)alloc(SB);
  // aliases (lifetimes verified):
  short* attn_cat = xq;            // written by attn (xq dead after QKV), read by Wo
  short* atto_bf  = xk;            // written by Wo (xk dead), read by W1 + W2(residual)
  short* h1       = xv;            // written by W1 (xv dead), read by W2
  float* yb       = (float*)qw;    // spans qw+kw (25.2 MB), written by W2, read by LN

  dim3 blk(256);
  // 1. prep: weight transpose+cast + vlens + activation cvt (one dispatch)
  prep_k<<<dim3(21892), blk, 0, stream>>>(Wq, Wk, Wv, Wo, W1, W2,
                                          wt[0], wt[1], wt[2], wt[3], wt[4], wt[5],
                                          mask, vlens,
                                          queries, keys, values, xq, xk, xv);
  // 2. fused QKV projections (Q pre-scaled by QSCALE; V transposed)
  gemm_k<EPI_QKV><<<dim3(128, 6, 3), blk, 0, stream>>>(
      xq, xk, xv, wt[0], wt[1], wt[2], nullptr, nullptr, qw, kw, vtw);
  // 3. flash attention (S^T form, 64-row Q tile)
  attn_k<<<dim3(48, 32), blk, 0, stream>>>(qw, kw, vtw, vlens, attn_cat);
  // 4. Wo projection (bf16 out; doubles as residual)
  gemm_k<EPI_PLAIN><<<dim3(128, 6, 1), blk, 0, stream>>>(
      attn_cat, nullptr, nullptr, wt[3], nullptr, nullptr, nullptr, nullptr,
      atto_bf, nullptr, nullptr);
  // 5. FFN layer 1 (bias + relu)
  gemm_k<EPI_BIAS_RELU><<<dim3(128, 6, 1), blk, 0, stream>>>(
      atto_bf, nullptr, nullptr, wt[4], nullptr, nullptr, b1, nullptr,
      h1, nullptr, nullptr);
  // 6. FFN layer 2 + bias + bf16 residual -> y (f32)
  gemm_k<EPI_Y><<<dim3(128, 6, 1), blk, 0, stream>>>(
      h1, nullptr, nullptr, wt[5], nullptr, nullptr, b2, atto_bf,
      yb, nullptr, nullptr);
  // 7. layernorm -> output
  ln_k<<<dim3(MROWS), blk, 0, stream>>>(yb, ln_g, ln_b, (float*)d_out);
}

// Round 10
// 304.553 us; speedup vs baseline: 1.0543x; 1.0543x over previous
//
#include <hip/hip_runtime.h>
#include <stdint.h>

typedef __attribute__((ext_vector_type(4))) float floatx4;
typedef __attribute__((ext_vector_type(8))) __bf16 bf16x8;
typedef __attribute__((ext_vector_type(4))) short short4v;

#define DEV __device__ __forceinline__

constexpr int HB = 12;        // heads
constexpr int LSEQ = 2048;    // LQ == LK
constexpr int DMODEL = 768;
constexpr int MROWS = 8192;   // B * LQ
constexpr float QSCALE = 0.125f * 1.44269504088896f;  // 1/sqrt(64) * log2(e)

DEV short f2bf(float f) {
  union { float f; uint32_t u; } x; x.f = f;
  uint32_t r = x.u + 0x7FFFu + ((x.u >> 16) & 1u);
  return (short)(r >> 16);
}

DEV float bf2f(short s) {
  union { uint32_t u; float f; } x; x.u = ((uint32_t)(uint16_t)s) << 16;
  return x.f;
}

typedef __attribute__((address_space(1))) void as1_void;
typedef __attribute__((address_space(3))) void as3_void;

DEV void gload_lds16(const void* g, void* l) {
  __builtin_amdgcn_global_load_lds((as1_void*)(uintptr_t)g, (as3_void*)l, 16, 0, 0);
}

// ---------------------------------------------------------------- prep (weight T + vlens + activation cvt)
// flat grid: [0,3456) weight transposes, [3456,3460) vlens, [3460,21892) f32->bf16 cvt
__global__ __launch_bounds__(256)
void prep_k(const float* w0, const float* w1, const float* w2,
            const float* w3, const float* w4, const float* w5,
            short* o0, short* o1, short* o2, short* o3, short* o4, short* o5,
            const int* __restrict__ mask, int* __restrict__ vl,
            const float* __restrict__ aq, const float* __restrict__ ak, const float* __restrict__ av,
            short* __restrict__ dq, short* __restrict__ dk, short* __restrict__ dv)
{
  const int id = blockIdx.x;
  if (id >= 3460) {                       // activation cast
    const int cid = id - 3460;
    const int t = cid / 6144, inner = cid % 6144;
    const float* s = (t == 0) ? aq : (t == 1) ? ak : av;
    short* d = (t == 0) ? dq : (t == 1) ? dk : dv;
    const size_t i = ((size_t)inner * 256 + threadIdx.x) * 4;
    const float4 v = *(const float4*)(s + i);
    short4 r; r.x = f2bf(v.x); r.y = f2bf(v.y); r.z = f2bf(v.z); r.w = f2bf(v.w);
    *(short4*)(d + i) = r;
    return;
  }
  if (id >= 3456) {                       // valid lengths
    const int b = id - 3456;
    int s = 0;
    for (int i = threadIdx.x; i < LSEQ; i += 256) s += (mask[b * LSEQ + i] != 0) ? 1 : 0;
#pragma unroll
    for (int o = 32; o >= 1; o >>= 1) s += __shfl_xor(s, o);
    __shared__ int red[4];
    const int lane = threadIdx.x & 63, wave = threadIdx.x >> 6;
    if (lane == 0) red[wave] = s;
    __syncthreads();
    if (threadIdx.x == 0) vl[b] = red[0] + red[1] + red[2] + red[3];
    return;
  }
  const int slice = id / 576, rem = id % 576;   // weight transpose+cast
  const float* W; short* O;
  switch (slice) {
    case 0: W = w0; O = o0; break;
    case 1: W = w1; O = o1; break;
    case 2: W = w2; O = o2; break;
    case 3: W = w3; O = o3; break;
    case 4: W = w4; O = o4; break;
    default: W = w5; O = o5; break;
  }
  __shared__ float t[32][33];
  const int tx = threadIdx.x & 31, ty = threadIdx.x >> 5; // 32 x 8
  const int n0 = (rem % 24) * 32, k0 = (rem / 24) * 32;
#pragma unroll
  for (int i = 0; i < 4; ++i)
    t[ty + i * 8][tx] = W[(size_t)(k0 + ty + i * 8) * DMODEL + n0 + tx];
  __syncthreads();
#pragma unroll
  for (int i = 0; i < 4; ++i)
    O[(size_t)(n0 + ty + i * 8) * DMODEL + k0 + tx] = f2bf(t[tx][ty + i * 8]);
}

// ---------------------------------------------------------------- GEMM
// r6/r8 PROVEN OPTIMUM of this family: 64x128 tile, BK=64 (2x32 halves),
// double-buffered ping-pong, raw s_barrier + vmcnt(6), 16 MFMA + 6 loads per
// barrier-pair, 48 KB LDS -> 3 blocks/CU.
// Mapped failure modes (do not redo): r7 BK=32 tri-buffer (less MFMA/barrier,
// 4 blk/CU) -> 78 us; r9 BK=64 tri-buffer prefetch-2 (2 blk/CU) -> 69 us.
// TLP at >=3 blocks/CU is the binding constraint.
enum { EPI_QKV = 0, EPI_PLAIN = 2, EPI_BIAS_RELU = 3, EPI_Y = 4 };

template <int EPI>
__global__ __launch_bounds__(256)
void gemm_k(const short* __restrict__ A0, const short* __restrict__ A1, const short* __restrict__ A2,
            const short* __restrict__ B0, const short* __restrict__ B1, const short* __restrict__ B2,
            const float* __restrict__ bias, const short* __restrict__ resid,
            void* __restrict__ o0, void* __restrict__ o1, void* __restrict__ o2)
{
  __shared__ __align__(16) short As[2][2][64 * 32];    // [buf][half] 16 KB
  __shared__ __align__(16) short Bs[2][2][128 * 32];   // [buf][half] 32 KB
  const short* A = A0;
  const short* Bt = B0;
  if constexpr (EPI == EPI_QKV) {
    if (blockIdx.z == 1) { A = A1; Bt = B1; }
    else if (blockIdx.z == 2) { A = A2; Bt = B2; }
  }
  const int tid = threadIdx.x;
  const int lane = tid & 63, wave = tid >> 6;
  const int wm = wave >> 1, wn = wave & 1;
  const int m0 = blockIdx.x * 64, n0 = blockIdx.y * 128;   // x = m-panel (XCD affinity)
  const int col = lane & 15, quad = lane >> 4;
  const int sr = lane >> 2;            // staging row within 16-row chunk
  const int sk = (lane & 3) * 8;       // staging k offset (8 bf16 = 16B)

  const short* Arow = A + (size_t)(m0 + wave * 16 + sr) * DMODEL + sk;
  const short* Brow0 = Bt + (size_t)(n0 + (wave * 2 + 0) * 16 + sr) * DMODEL + sk;
  const short* Brow1 = Bt + (size_t)(n0 + (wave * 2 + 1) * 16 + sr) * DMODEL + sk;

  auto stage = [&](int kt, int buf) {
    const int k0 = kt * 64;
#pragma unroll
    for (int h = 0; h < 2; ++h) {
      gload_lds16(Arow + k0 + h * 32, &As[buf][h][wave * 512]);
      gload_lds16(Brow0 + k0 + h * 32, &Bs[buf][h][(wave * 2 + 0) * 512]);
      gload_lds16(Brow1 + k0 + h * 32, &Bs[buf][h][(wave * 2 + 1) * 512]);
    }
  };

  floatx4 acc[2][4] = {};

  stage(0, 0);
  for (int kt = 0; kt < 12; ++kt) {
    const int cur = kt & 1;
    asm volatile("s_barrier" ::: "memory");
    if (kt + 1 < 12) {
      stage(kt + 1, cur ^ 1);
      asm volatile("s_waitcnt vmcnt(6)" ::: "memory");
    } else {
      asm volatile("s_waitcnt vmcnt(0)" ::: "memory");
    }
    asm volatile("s_barrier" ::: "memory");
#pragma unroll
    for (int h = 0; h < 2; ++h) {
      bf16x8 af[2], bfr[4];
#pragma unroll
      for (int t = 0; t < 2; ++t)
        af[t] = *(const bf16x8*)&As[cur][h][(wm * 32 + t * 16 + col) * 32 + quad * 8];
#pragma unroll
      for (int t = 0; t < 4; ++t)
        bfr[t] = *(const bf16x8*)&Bs[cur][h][(wn * 64 + t * 16 + col) * 32 + quad * 8];
#pragma unroll
      for (int mt = 0; mt < 2; ++mt)
#pragma unroll
        for (int nt = 0; nt < 4; ++nt)
          acc[mt][nt] = __builtin_amdgcn_mfma_f32_16x16x32_bf16(af[mt], bfr[nt], acc[mt][nt], 0, 0, 0);
    }
  }

#pragma unroll
  for (int mt = 0; mt < 2; ++mt) {
#pragma unroll
    for (int nt = 0; nt < 4; ++nt) {
#pragma unroll
      for (int r = 0; r < 4; ++r) {
        const int m = m0 + wm * 32 + mt * 16 + quad * 4 + r;
        const int n = n0 + wn * 64 + nt * 16 + col;
        float v = acc[mt][nt][r];
        if constexpr (EPI == EPI_QKV) {
          const int b = m >> 11, l = m & 2047, h = n >> 6, dh = n & 63;
          const int z = blockIdx.z;
          if (z == 0) {
            ((short*)o0)[((size_t)(b * HB + h) * LSEQ + l) * 64 + dh] = f2bf(v * QSCALE);
          } else if (z == 1) {
            ((short*)o1)[((size_t)(b * HB + h) * LSEQ + l) * 64 + dh] = f2bf(v);
          } else {
            ((short*)o2)[((size_t)(b * HB + h) * 64 + dh) * LSEQ + l] = f2bf(v);
          }
        } else if constexpr (EPI == EPI_PLAIN) {
          ((short*)o0)[(size_t)m * DMODEL + n] = f2bf(v);
        } else if constexpr (EPI == EPI_BIAS_RELU) {
          v += bias[n]; v = v > 0.f ? v : 0.f;
          ((short*)o0)[(size_t)m * DMODEL + n] = f2bf(v);
        } else { // EPI_Y: + bias + bf16 residual -> bf16 y (LN re-reads bf16: halves y traffic)
          v += bias[n] + bf2f(resid[(size_t)m * DMODEL + n]);
          ((short*)o0)[(size_t)m * DMODEL + n] = f2bf(v);
        }
      }
    }
  }
}

// ---------------------------------------------------------------- flash attention (S^T form)
// 64-row Q tile, grid 48x32 = 1536 blocks. S^T = K Q^T; P^T feeds 16x16x16 PV
// from registers; Q in registers; Vts XOR-swizzled; dbuf K/V ping-pong vmcnt(4).
__global__ __launch_bounds__(256)
void attn_k(const short* __restrict__ qw, const short* __restrict__ kw, const short* __restrict__ vtw,
            const int* __restrict__ vlens, short* __restrict__ outp)
{
  __shared__ __align__(16) short Ks[2][2][64][32];      // [buf][dh-half][kpos]  16 KB
  __shared__ __align__(16) short Vts[2][2][64][32];     // [buf][kp-half][dh]    16 KB (swizzled)

  const int tid = threadIdx.x;
  const int lane = tid & 63, wave = tid >> 6;
  const int col = lane & 15, quad = lane >> 4;
  const int bh = blockIdx.x, b = bh / HB, h = bh % HB;
  const int q0 = blockIdx.y * 64;
  const int vl = vlens[b];
  const int sr = lane >> 2, sk = (lane & 3) * 8;
  const int skv = ((lane & 3) ^ ((lane >> 3) & 3)) * 8;   // V staging swizzle (lane-const)
  const int swz = (col >> 1) & 3;                          // V read swizzle

  const short* qbase = qw  + (size_t)bh * LSEQ * 64;
  const short* kbase = kw  + (size_t)bh * LSEQ * 64;
  const short* vbase = vtw + (size_t)bh * 64 * LSEQ;

  // Q fragments direct to registers (per-wave rows q0 + wave*16 .. +15)
  bf16x8 qf[2];
#pragma unroll
  for (int ks = 0; ks < 2; ++ks)
    qf[ks] = *(const bf16x8*)(qbase + (size_t)(q0 + wave * 16 + col) * 64 + ks * 32 + quad * 8);

  auto stage = [&](int kt, int buf) {
#pragma unroll
    for (int i = 0; i < 2; ++i) {
      const int c = wave * 2 + i;        // 0..7
      const int hs = c >> 2, r0 = (c & 3) * 16;
      gload_lds16(kbase + (size_t)(kt * 64 + r0 + sr) * 64 + hs * 32 + sk, &Ks[buf][hs][r0][0]);
      gload_lds16(vbase + (size_t)(r0 + sr) * LSEQ + kt * 64 + hs * 32 + skv, &Vts[buf][hs][r0][0]);
    }
  };

  floatx4 oacc[4] = {};   // [d-chunk nt], O^T C-layout
  float li = 0.f;         // per-lane partial denominator (q = col)

  const int ktend = (vl > 0) ? ((vl + 63) >> 6) : (LSEQ / 64);

  stage(0, 0);
  for (int kt = 0; kt < ktend; ++kt) {
    const int cur = kt & 1;
    asm volatile("s_barrier" ::: "memory");
    if (kt + 1 < ktend) {
      stage(kt + 1, cur ^ 1);
      asm volatile("s_waitcnt vmcnt(4)" ::: "memory");   // tile-kt's 4 loads landed
    } else {
      asm volatile("s_waitcnt vmcnt(0)" ::: "memory");
    }
    asm volatile("s_barrier" ::: "memory");

    // S^T = K Q^T : sacc[kc], rows = kpos, cols = q
    floatx4 sacc[4] = {};
#pragma unroll
    for (int ks = 0; ks < 2; ++ks) {
      bf16x8 kf[4];
#pragma unroll
      for (int kc = 0; kc < 4; ++kc)
        kf[kc] = *(const bf16x8*)&Ks[cur][ks][kc * 16 + col][quad * 8];
#pragma unroll
      for (int kc = 0; kc < 4; ++kc)
        sacc[kc] = __builtin_amdgcn_mfma_f32_16x16x32_bf16(kf[kc], qf[ks], sacc[kc], 0, 0, 0);
    }

    // boundary tile: masked kpos rows -> -1e6 (exp2 -> exactly 0, = ref)
    if (kt * 64 + 64 > vl) {
#pragma unroll
      for (int kc = 0; kc < 4; ++kc) {
        const int pbase = kt * 64 + kc * 16 + quad * 4;
#pragma unroll
        for (int r = 0; r < 4; ++r) {
          const bool ok = (pbase + r) < vl;
          sacc[kc][r] = ok ? sacc[kc][r] : -1.0e6f;
        }
      }
    }

    // p = exp2(s); accumulate per-lane denominator; pack to bf16 B-frags
    short4v pf[4];
#pragma unroll
    for (int kc = 0; kc < 4; ++kc) {
      union { float f; uint32_t u; } p0, p1, p2, p3;
      p0.f = __builtin_amdgcn_exp2f(sacc[kc][0]);
      p1.f = __builtin_amdgcn_exp2f(sacc[kc][1]);
      p2.f = __builtin_amdgcn_exp2f(sacc[kc][2]);
      p3.f = __builtin_amdgcn_exp2f(sacc[kc][3]);
      li += (p0.f + p1.f) + (p2.f + p3.f);
      union { int2 i2; short4v s4; } pk;
      pk.i2.x = (int)__builtin_amdgcn_perm(p1.u, p0.u, 0x07060302u);  // {hi16(p1),hi16(p0)}
      pk.i2.y = (int)__builtin_amdgcn_perm(p3.u, p2.u, 0x07060302u);
      pf[kc] = pk.s4;
    }

    // O^T += V^T P^T via K=16 MFMA (P^T chunks are already B-operand layout)
#pragma unroll
    for (int nt = 0; nt < 4; ++nt) {
      short4v vf[4];
#pragma unroll
      for (int kc = 0; kc < 4; ++kc) {
        const int jb = (((kc & 1) * 2 + (quad >> 1)) ^ swz);
        vf[kc] = *(const short4v*)&Vts[cur][kc >> 1][nt * 16 + col][jb * 8 + (quad & 1) * 4];
      }
#pragma unroll
      for (int kc = 0; kc < 4; ++kc)
        oacc[nt] = __builtin_amdgcn_mfma_f32_16x16x16bf16_1k(vf[kc], pf[kc], oacc[nt], 0, 0, 0);
    }
  }

  // reduce denominator across quads (q = col is lane-resident)
  float t = li;
  t += __shfl_xor(t, 16);
  t += __shfl_xor(t, 32);
  const float rli = 1.0f / fmaxf(t, 1e-30f);

  // epilogue: O[q][d] from O^T C-layout; d contiguous -> b64 stores
  const int q = q0 + wave * 16 + col;
  short* orow = outp + ((size_t)b * LSEQ + q) * DMODEL + h * 64 + quad * 4;
#pragma unroll
  for (int nt = 0; nt < 4; ++nt) {
    short4 s;
    s.x = f2bf(oacc[nt][0] * rli);
    s.y = f2bf(oacc[nt][1] * rli);
    s.z = f2bf(oacc[nt][2] * rli);
    s.w = f2bf(oacc[nt][3] * rli);
    *(short4*)(orow + nt * 16) = s;
  }
}

// ---------------------------------------------------------------- layernorm (bf16 y in, f32 out)
__global__ __launch_bounds__(256)
void ln_k(const short* __restrict__ y, const float* __restrict__ g, const float* __restrict__ be,
          float* __restrict__ o)
{
  const int row = blockIdx.x;
  const int tid = threadIdx.x;
  const short* yr = y + (size_t)row * DMODEL;
  float v[3];
  float s = 0.f, sq = 0.f;
#pragma unroll
  for (int i = 0; i < 3; ++i) { v[i] = bf2f(yr[tid + i * 256]); s += v[i]; sq += v[i] * v[i]; }
#pragma unroll
  for (int off = 32; off >= 1; off >>= 1) { s += __shfl_xor(s, off); sq += __shfl_xor(sq, off); }
  __shared__ float red[8];
  const int lane = tid & 63, wave = tid >> 6;
  if (lane == 0) { red[wave] = s; red[4 + wave] = sq; }
  __syncthreads();
  s = red[0] + red[1] + red[2] + red[3];
  sq = red[4] + red[5] + red[6] + red[7];
  const float mu = s * (1.f / 768.f);
  const float var = sq * (1.f / 768.f) - mu * mu;
  const float rstd = rsqrtf(var + 1e-5f);
  float* orow = o + (size_t)row * DMODEL;
#pragma unroll
  for (int i = 0; i < 3; ++i) {
    const int c = tid + i * 256;
    orow[c] = (v[i] - mu) * rstd * g[c] + be[c];
  }
}

// ---------------------------------------------------------------- launch
extern "C" void kernel_launch(void* const* d_in, const int* in_sizes, int n_in,
                              void* d_out, int out_size, void* d_ws, size_t ws_size,
                              hipStream_t stream)
{
  const float* queries = (const float*)d_in[0];
  const float* keys    = (const float*)d_in[1];
  const float* values  = (const float*)d_in[2];
  const int*   mask    = (const int*)d_in[3];
  const float* Wq = (const float*)d_in[4];
  const float* Wk = (const float*)d_in[5];
  const float* Wv = (const float*)d_in[6];
  const float* Wo = (const float*)d_in[7];
  const float* W1 = (const float*)d_in[8];
  const float* b1 = (const float*)d_in[9];
  const float* W2 = (const float*)d_in[10];
  const float* b2 = (const float*)d_in[11];
  const float* ln_g = (const float*)d_in[12];
  const float* ln_b = (const float*)d_in[13];

  char* ws = (char*)d_ws;
  size_t off = 0;
  auto alloc = [&](size_t bytes) -> void* {
    void* p = ws + off;
    off = (off + bytes + 255) & ~(size_t)255;
    return p;
  };
  int* vlens = (int*)alloc(256);
  short* wt[6];
  for (int i = 0; i < 6; ++i) wt[i] = (short*)alloc((size_t)DMODEL * DMODEL * 2);
  constexpr size_t SB = (size_t)MROWS * DMODEL * 2;  // 12,582,912 (multiple of 256)
  short* xq  = (short*)alloc(SB);
  short* xk  = (short*)alloc(SB);
  short* xv  = (short*)alloc(SB);
  short* qw  = (short*)alloc(SB);
  short* kw  = (short*)alloc(SB);
  short* vtw = (short*)alloc(SB);
  // aliases (lifetimes verified):
  short* attn_cat = xq;            // written by attn (xq dead after QKV), read by Wo
  short* atto_bf  = xk;            // written by Wo (xk dead), read by W1 + W2(residual)
  short* h1       = xv;            // written by W1 (xv dead), read by W2
  short* yb       = qw;            // bf16 y (12.5 MB), written by W2, read by LN

  dim3 blk(256);
  // 1. prep: weight transpose+cast + vlens + activation cvt (one dispatch)
  prep_k<<<dim3(21892), blk, 0, stream>>>(Wq, Wk, Wv, Wo, W1, W2,
                                          wt[0], wt[1], wt[2], wt[3], wt[4], wt[5],
                                          mask, vlens,
                                          queries, keys, values, xq, xk, xv);
  // 2. fused QKV projections (Q pre-scaled by QSCALE; V transposed)
  gemm_k<EPI_QKV><<<dim3(128, 6, 3), blk, 0, stream>>>(
      xq, xk, xv, wt[0], wt[1], wt[2], nullptr, nullptr, qw, kw, vtw);
  // 3. flash attention (S^T form, 64-row Q tile)
  attn_k<<<dim3(48, 32), blk, 0, stream>>>(qw, kw, vtw, vlens, attn_cat);
  // 4. Wo projection (bf16 out; doubles as residual)
  gemm_k<EPI_PLAIN><<<dim3(128, 6, 1), blk, 0, stream>>>(
      attn_cat, nullptr, nullptr, wt[3], nullptr, nullptr, nullptr, nullptr,
      atto_bf, nullptr, nullptr);
  // 5. FFN layer 1 (bias + relu)
  gemm_k<EPI_BIAS_RELU><<<dim3(128, 6, 1), blk, 0, stream>>>(
      atto_bf, nullptr, nullptr, wt[4], nullptr, nullptr, b1, nullptr,
      h1, nullptr, nullptr);
  // 6. FFN layer 2 + bias + bf16 residual -> y (bf16)
  gemm_k<EPI_Y><<<dim3(128, 6, 1), blk, 0, stream>>>(
      h1, nullptr, nullptr, wt[5], nullptr, nullptr, b2, atto_bf,
      yb, nullptr, nullptr);
  // 7. layernorm -> output
  ln_k<<<dim3(MROWS), blk, 0, stream>>>(yb, ln_g, ln_b, (float*)d_out);
}